// Round 1
// baseline (233.358 us; speedup 1.0000x reference)
//
#include <hip/hip_runtime.h>
#include <hip/hip_bf16.h>
#include <math.h>

#define N_ 64
#define S_ 512
#define D_ 768
#define C_ 32

// ---------------------------------------------------------------------------
// K1: npots = X @ W   (M = N*S = 32768 rows, K = 768, 32 cols)
// 64-row x 32-col tile per block, 256 threads, K staged in 64-chunks via LDS.
// ---------------------------------------------------------------------------
__global__ __launch_bounds__(256) void gemm_npots(const float* __restrict__ X,
                                                  const float* __restrict__ W,
                                                  float* __restrict__ npots) {
    __shared__ float Xs[64][68];   // +4 pad: float4-aligned, bank shift 4
    __shared__ float Ws[64][36];
    const int tid  = threadIdx.x;
    const int row0 = blockIdx.x * 64;
    // compute mapping: 4 rows x 2 cols per thread
    const int c2 = tid & 15;        // col pair index (cols 2*c2, 2*c2+1)
    const int rq = tid >> 4;        // row quad index (rows 4*rq .. 4*rq+3)
    // load mappings
    const int f    = tid & 15;      // float4 index within X row chunk
    const int rldr = tid >> 4;      // base row for X loads
    const int c4   = tid & 7;       // float4 index within W row
    const int kw   = tid >> 3;      // base k for W loads

    float acc[4][2] = {{0.f,0.f},{0.f,0.f},{0.f,0.f},{0.f,0.f}};

    for (int k0 = 0; k0 < D_; k0 += 64) {
        #pragma unroll
        for (int rr = 0; rr < 4; ++rr) {
            const int r = rldr + rr * 16;
            const float4 v = *(const float4*)(X + (size_t)(row0 + r) * D_ + k0 + f * 4);
            *(float4*)&Xs[r][f * 4] = v;
        }
        #pragma unroll
        for (int kk = 0; kk < 2; ++kk) {
            const int k = kw + kk * 32;
            const float4 v = *(const float4*)(W + (size_t)(k0 + k) * C_ + c4 * 4);
            *(float4*)&Ws[k][c4 * 4] = v;
        }
        __syncthreads();
        #pragma unroll 8
        for (int kk = 0; kk < 64; ++kk) {
            const float w0 = Ws[kk][c2 * 2];
            const float w1 = Ws[kk][c2 * 2 + 1];
            #pragma unroll
            for (int i = 0; i < 4; ++i) {
                const float x = Xs[rq * 4 + i][kk];
                acc[i][0] = fmaf(x, w0, acc[i][0]);
                acc[i][1] = fmaf(x, w1, acc[i][1]);
            }
        }
        __syncthreads();
    }
    #pragma unroll
    for (int i = 0; i < 4; ++i) {
        float2 o = make_float2(acc[i][0], acc[i][1]);
        *(float2*)(npots + (size_t)(row0 + rq * 4 + i) * C_ + c2 * 2) = o;
    }
}

// ---------------------------------------------------------------------------
// K2: backward recursion in LINEAR space with periodic renormalization.
// One wave (64 lanes) per sequence n. Lane l: c = l&31, half h = l>>5.
// State u[c] (= exp(msg[c] - logscale)); w = exp(npots[t]) * u kept in LDS.
// msg_i[c] = LSE_{c'}( npots[i+1,c'] + T[c,c'] + msg_{i+1}[c'] )
//  => u_i = ET . (exp(npots[i+1]) * u_{i+1}),  ET = exp(T)
// Padding is a suffix: start at i = len-2 with u = 1 (msg = 0).
// logZ = log( sum_c exp(npots[0,c]) * u_0[c] ) + logscale
// ---------------------------------------------------------------------------
__global__ __launch_bounds__(64) void scan_logZ(const float* __restrict__ npots,
                                                const float* __restrict__ pad,
                                                const float* __restrict__ T,
                                                float* __restrict__ logZ) {
    const int n = blockIdx.x;
    const int l = threadIdx.x;
    const int c = l & 31;
    const int h = l >> 5;
    __shared__ __align__(16) float w_lds[32];

    // ET row c, halves of 16 columns per lane
    float ETr[16];
    #pragma unroll
    for (int j = 0; j < 16; ++j) ETr[j] = expf(T[c * C_ + h * 16 + j]);

    // sequence length = sum of pad row (exact 0/1 floats)
    const float* pm = pad + (size_t)n * S_;
    float ls = 0.f;
    for (int t = l; t < S_; t += 64) ls += pm[t];
    #pragma unroll
    for (int o = 32; o >= 1; o >>= 1) ls += __shfl_xor(ls, o);
    const int len = (int)(ls + 0.5f);

    const float* np_n = npots + (size_t)n * S_ * C_;
    float logscale = 0.f;

    if (h == 0) w_lds[c] = expf(np_n[(size_t)(len - 1) * C_ + c]);   // w = exp(npots[len-1]) * 1
    __syncthreads();

    float u = 0.f;
    for (int i = len - 2; i >= 0; --i) {
        const float npv = np_n[(size_t)i * C_ + c];   // prefetch for next w (and np0 at i=0)
        const float4 w0 = *(const float4*)&w_lds[h * 16];
        const float4 w1 = *(const float4*)&w_lds[h * 16 + 4];
        const float4 w2 = *(const float4*)&w_lds[h * 16 + 8];
        const float4 w3 = *(const float4*)&w_lds[h * 16 + 12];
        float s0 = ETr[0] * w0.x;
        s0 = fmaf(ETr[1], w0.y, s0); s0 = fmaf(ETr[2], w0.z, s0); s0 = fmaf(ETr[3], w0.w, s0);
        float s1 = ETr[4] * w1.x;
        s1 = fmaf(ETr[5], w1.y, s1); s1 = fmaf(ETr[6], w1.z, s1); s1 = fmaf(ETr[7], w1.w, s1);
        float s2 = ETr[8] * w2.x;
        s2 = fmaf(ETr[9], w2.y, s2); s2 = fmaf(ETr[10], w2.z, s2); s2 = fmaf(ETr[11], w2.w, s2);
        float s3 = ETr[12] * w3.x;
        s3 = fmaf(ETr[13], w3.y, s3); s3 = fmaf(ETr[14], w3.z, s3); s3 = fmaf(ETr[15], w3.w, s3);
        float s = (s0 + s1) + (s2 + s3);
        s += __shfl_xor(s, 32);       // combine the two 16-wide halves -> u_i[c] in all lanes

        if ((i & 7) == 0) {           // renormalize every 8 steps
            float m = s;
            #pragma unroll
            for (int o = 16; o >= 1; o >>= 1) m = fmaxf(m, __shfl_xor(m, o));
            logscale += logf(m);
            s /= m;
        }
        __syncthreads();              // all reads of old w done
        if (i > 0) {
            if (h == 0) w_lds[c] = s * expf(npv);
        } else {
            u = s;
        }
        __syncthreads();              // new w visible
    }

    // logZ
    const float np0 = np_n[c];
    float m0 = np0;
    #pragma unroll
    for (int o = 16; o >= 1; o >>= 1) m0 = fmaxf(m0, __shfl_xor(m0, o));
    float z = expf(np0 - m0) * u;
    #pragma unroll
    for (int o = 16; o >= 1; o >>= 1) z += __shfl_xor(z, o);
    if (l == 0) logZ[n] = logf(z) + m0 + logscale;
}

// ---------------------------------------------------------------------------
// K3: score_n = sum_t pad[t]*npots[t,lab_t] + sum_{t>=1} pad[t]*T[lab_{t-1},lab_t]
// one block per n, 256 threads (8 t-rows x 32 c per sweep).
// ---------------------------------------------------------------------------
__global__ __launch_bounds__(256) void score_kernel(const float* __restrict__ npots,
                                                    const float* __restrict__ labels,
                                                    const float* __restrict__ pad,
                                                    const float* __restrict__ T,
                                                    float* __restrict__ scores) {
    const int n = blockIdx.x;
    const int tid = threadIdx.x;
    __shared__ float Ts[C_ * C_];
    __shared__ int   idx_s[S_];
    __shared__ float red[4];

    for (int i = tid; i < C_ * C_; i += 256) Ts[i] = T[i];

    const int c  = tid & 31;
    const int t0 = tid >> 5;
    float emit = 0.f;
    for (int t = t0; t < S_; t += 8) {
        const size_t base = ((size_t)n * S_ + t) * C_ + c;
        const float lab = labels[base];
        const float npv = npots[base];
        const float p   = pad[(size_t)n * S_ + t];
        emit = fmaf(lab * npv, p, emit);       // one-hot dot: picks npots[t, lab_t]
        if (lab > 0.5f) idx_s[t] = c;
    }
    __syncthreads();

    float trans = 0.f;
    for (int t = 1 + tid; t < S_; t += 256) {
        const float p = pad[(size_t)n * S_ + t];
        trans = fmaf(p, Ts[idx_s[t - 1] * C_ + idx_s[t]], trans);
    }

    float v = emit + trans;
    #pragma unroll
    for (int o = 32; o >= 1; o >>= 1) v += __shfl_xor(v, o);
    if ((tid & 63) == 0) red[tid >> 6] = v;
    __syncthreads();
    if (tid == 0) scores[n] = red[0] + red[1] + red[2] + red[3];
}

// ---------------------------------------------------------------------------
// K4: loss = -mean(score - logZ)
// ---------------------------------------------------------------------------
__global__ __launch_bounds__(64) void finalize(const float* __restrict__ scores,
                                               const float* __restrict__ logZ,
                                               float* __restrict__ out) {
    const int l = threadIdx.x;
    float v = scores[l] - logZ[l];
    #pragma unroll
    for (int o = 32; o >= 1; o >>= 1) v += __shfl_xor(v, o);
    if (l == 0) out[0] = -v / (float)N_;
}

// ---------------------------------------------------------------------------
extern "C" void kernel_launch(void* const* d_in, const int* in_sizes, int n_in,
                              void* d_out, int out_size, void* d_ws, size_t ws_size,
                              hipStream_t stream) {
    const float* X      = (const float*)d_in[0];   // (N,S,D)
    const float* W      = (const float*)d_in[1];   // (D,C)
    const float* T      = (const float*)d_in[2];   // (C,C)
    const float* labels = (const float*)d_in[3];   // (N,S,C)
    const float* pad    = (const float*)d_in[4];   // (N,S)
    float* out = (float*)d_out;

    float* npots  = (float*)d_ws;                  // N*S*C floats = 4 MB
    float* logZ   = npots + (size_t)N_ * S_ * C_;  // N floats
    float* scores = logZ + N_;                     // N floats

    gemm_npots<<<(N_ * S_) / 64, 256, 0, stream>>>(X, W, npots);
    scan_logZ<<<N_, 64, 0, stream>>>(npots, pad, T, logZ);
    score_kernel<<<N_, 256, 0, stream>>>(npots, labels, pad, T, scores);
    finalize<<<1, 64, 0, stream>>>(scores, logZ, out);
}

// Round 2
// 127.280 us; speedup vs baseline: 1.8334x; 1.8334x over previous
//
#include <hip/hip_runtime.h>
#include <hip/hip_bf16.h>
#include <math.h>

#define N_ 64
#define S_ 512
#define D_ 768
#define C_ 32
#define KCH 16    // chunks per sequence
#define LC 32     // steps per chunk

// ---------------------------------------------------------------------------
// K1: npots = X @ W. 128-row x 32-col tile, 512 threads, k-chunk 32.
// Per thread: 2 rows (ra, ra+64) x 4 cols (4jq..4jq+3).
// ---------------------------------------------------------------------------
__global__ __launch_bounds__(512) void gemm_npots(const float* __restrict__ X,
                                                  const float* __restrict__ W,
                                                  float* __restrict__ npots) {
    __shared__ float Xs[128][36];   // pad 36: b128-aligned, conflict-free
    __shared__ float Ws[32][36];
    const int tid  = threadIdx.x;
    const int row0 = blockIdx.x * 128;
    const int f  = tid & 7;     // X-load float4 index within 32-k chunk
    const int rl = tid >> 3;    // X-load rows rl, rl+64
    const int kw = tid >> 4;    // W-load k
    const int c2 = tid & 15;    // W-load col pair
    const int ra = tid >> 3;    // compute rows ra, ra+64
    const int jq = tid & 7;     // compute cols 4jq..4jq+3

    float acc[2][4] = {};

    for (int k0 = 0; k0 < D_; k0 += 32) {
        {
            const float4 v0 = *(const float4*)(X + (size_t)(row0 + rl) * D_ + k0 + f * 4);
            const float4 v1 = *(const float4*)(X + (size_t)(row0 + rl + 64) * D_ + k0 + f * 4);
            *(float4*)&Xs[rl][f * 4]      = v0;
            *(float4*)&Xs[rl + 64][f * 4] = v1;
        }
        {
            const float2 w = *(const float2*)(W + (size_t)(k0 + kw) * C_ + c2 * 2);
            Ws[kw][c2 * 2]     = w.x;
            Ws[kw][c2 * 2 + 1] = w.y;
        }
        __syncthreads();
        #pragma unroll
        for (int kk = 0; kk < 32; kk += 4) {
            float x0[4], x1[4], wv[4][4];
            *(float4*)x0 = *(const float4*)&Xs[ra][kk];
            *(float4*)x1 = *(const float4*)&Xs[ra + 64][kk];
            #pragma unroll
            for (int t = 0; t < 4; ++t) *(float4*)wv[t] = *(const float4*)&Ws[kk + t][jq * 4];
            #pragma unroll
            for (int t = 0; t < 4; ++t) {
                #pragma unroll
                for (int b = 0; b < 4; ++b) {
                    acc[0][b] = fmaf(x0[t], wv[t][b], acc[0][b]);
                    acc[1][b] = fmaf(x1[t], wv[t][b], acc[1][b]);
                }
            }
        }
        __syncthreads();
    }
    #pragma unroll
    for (int i = 0; i < 2; ++i) {
        const float4 o = make_float4(acc[i][0], acc[i][1], acc[i][2], acc[i][3]);
        *(float4*)(npots + (size_t)(row0 + ra + 64 * i) * C_ + jq * 4) = o;
    }
}

// ---------------------------------------------------------------------------
// K2: per-chunk 32x32 matrix products of G_i = diag(e_i) * ET, i descending.
// Block (n,k), 1 wave. Lane (rq=l>>3, jq=l&7): rows {rq+8i}, cols 4jq..4jq+3.
// B_k = G_lo * ... * G_{hi-1},  hi = min(lo+LC, len-1). Identity if empty.
// ---------------------------------------------------------------------------
__global__ __launch_bounds__(64) void chunk_products(const float* __restrict__ npots,
                                                     const float* __restrict__ pad,
                                                     const float* __restrict__ T,
                                                     float* __restrict__ Bg,
                                                     float* __restrict__ chunk_ls) {
    const int n = blockIdx.x;
    const int k = blockIdx.y;
    const int l = threadIdx.x;
    const int rq = l >> 3;
    const int jq = l & 7;
    __shared__ float Bs[C_][36];
    __shared__ float e_lds[LC * C_];

    // sequence length
    const float* pm = pad + (size_t)n * S_;
    float ls = 0.f;
    for (int t = l; t < S_; t += 64) ls += pm[t];
    #pragma unroll
    for (int o = 32; o >= 1; o >>= 1) ls += __shfl_xor(ls, o);
    const int len = (int)(ls + 0.5f);

    float* Bout = Bg + ((size_t)n * KCH + k) * (C_ * C_);
    const int lo = k * LC;
    const int hi = min(lo + LC, len - 1);

    if (lo >= len - 1) {   // empty chunk -> identity
        #pragma unroll
        for (int i4 = 0; i4 < 4; ++i4) {
            const int r = rq + 8 * i4;
            const float4 v = make_float4(r == 4 * jq ? 1.f : 0.f,
                                         r == 4 * jq + 1 ? 1.f : 0.f,
                                         r == 4 * jq + 2 ? 1.f : 0.f,
                                         r == 4 * jq + 3 ? 1.f : 0.f);
            *(float4*)(Bout + r * C_ + 4 * jq) = v;
        }
        if (l == 0) chunk_ls[n * KCH + k] = 0.f;
        return;
    }

    // ET rows rq+8i in registers (static indexing only)
    float ETr[4][32];
    #pragma unroll
    for (int i4 = 0; i4 < 4; ++i4) {
        #pragma unroll
        for (int c = 0; c < C_; ++c) ETr[i4][c] = expf(T[(rq + 8 * i4) * C_ + c]);
    }

    // stage e = exp(npots) rows lo..hi-1
    const int cnt = hi - lo;
    const float* npn = npots + ((size_t)n * S_ + lo) * C_;
    for (int q = l * 4; q < cnt * C_; q += 256) {
        float4 v = *(const float4*)(npn + q);
        v.x = expf(v.x); v.y = expf(v.y); v.z = expf(v.z); v.w = expf(v.w);
        *(float4*)&e_lds[q] = v;
    }
    __syncthreads();

    // init B = G_{hi-1} = diag(e_{hi-1}) * ET
    float acc[4][4];
    #pragma unroll
    for (int i4 = 0; i4 < 4; ++i4) {
        const float er = e_lds[(cnt - 1) * C_ + rq + 8 * i4];
        #pragma unroll
        for (int b = 0; b < 4; ++b) acc[i4][b] = er * ETr[i4][4 * jq + b];
    }

    float logscale = 0.f;
    int it = 0;
    for (int i = hi - 2; i >= lo; --i) {
        #pragma unroll
        for (int i4 = 0; i4 < 4; ++i4)
            *(float4*)&Bs[rq + 8 * i4][4 * jq] =
                make_float4(acc[i4][0], acc[i4][1], acc[i4][2], acc[i4][3]);
        __syncthreads();

        float nacc[4][4] = {};
        #pragma unroll
        for (int c = 0; c < C_; ++c) {
            float bv[4];
            *(float4*)bv = *(const float4*)&Bs[c][4 * jq];
            #pragma unroll
            for (int i4 = 0; i4 < 4; ++i4) {
                const float et = ETr[i4][c];
                #pragma unroll
                for (int b = 0; b < 4; ++b) nacc[i4][b] = fmaf(et, bv[b], nacc[i4][b]);
            }
        }
        const int row_e = (i - lo) * C_;
        #pragma unroll
        for (int i4 = 0; i4 < 4; ++i4) {
            const float er = e_lds[row_e + rq + 8 * i4];
            #pragma unroll
            for (int b = 0; b < 4; ++b) acc[i4][b] = er * nacc[i4][b];
        }

        if ((++it & 7) == 0) {   // renormalize every 8 steps
            float m = acc[0][0];
            #pragma unroll
            for (int i4 = 0; i4 < 4; ++i4)
                #pragma unroll
                for (int b = 0; b < 4; ++b) m = fmaxf(m, acc[i4][b]);
            #pragma unroll
            for (int o = 32; o >= 1; o >>= 1) m = fmaxf(m, __shfl_xor(m, o));
            logscale += logf(m);
            const float inv = 1.f / m;
            #pragma unroll
            for (int i4 = 0; i4 < 4; ++i4)
                #pragma unroll
                for (int b = 0; b < 4; ++b) acc[i4][b] *= inv;
        }
        __syncthreads();   // reads of Bs done before next store
    }

    // final renorm + store
    float m = acc[0][0];
    #pragma unroll
    for (int i4 = 0; i4 < 4; ++i4)
        #pragma unroll
        for (int b = 0; b < 4; ++b) m = fmaxf(m, acc[i4][b]);
    #pragma unroll
    for (int o = 32; o >= 1; o >>= 1) m = fmaxf(m, __shfl_xor(m, o));
    logscale += logf(m);
    const float inv = 1.f / m;
    #pragma unroll
    for (int i4 = 0; i4 < 4; ++i4) {
        const float4 v = make_float4(acc[i4][0] * inv, acc[i4][1] * inv,
                                     acc[i4][2] * inv, acc[i4][3] * inv);
        *(float4*)(Bout + (rq + 8 * i4) * C_ + 4 * jq) = v;
    }
    if (l == 0) chunk_ls[n * KCH + k] = logscale;
}

// ---------------------------------------------------------------------------
// K3: apply B_{K-1}..B_0 to e_{len-1}; logZ = log(sum w) + logscales.
// One wave per n. Lane (r=l&31, h=l>>5).
// ---------------------------------------------------------------------------
__global__ __launch_bounds__(64) void combine_logZ(const float* __restrict__ npots,
                                                   const float* __restrict__ pad,
                                                   const float* __restrict__ Bg,
                                                   const float* __restrict__ chunk_ls,
                                                   float* __restrict__ logZ) {
    const int n = blockIdx.x;
    const int l = threadIdx.x;
    const int r = l & 31;
    const int h = l >> 5;
    __shared__ __align__(16) float w_lds[32];

    const float* pm = pad + (size_t)n * S_;
    float ls = 0.f;
    for (int t = l; t < S_; t += 64) ls += pm[t];
    #pragma unroll
    for (int o = 32; o >= 1; o >>= 1) ls += __shfl_xor(ls, o);
    const int len = (int)(ls + 0.5f);

    // sum of chunk logscales
    float cls = (l < KCH) ? chunk_ls[n * KCH + l] : 0.f;
    #pragma unroll
    for (int o = 32; o >= 1; o >>= 1) cls += __shfl_xor(cls, o);

    // init w = exp(npots[len-1] - m0)
    const float np_last = npots[((size_t)n * S_ + (len - 1)) * C_ + r];
    float m0 = np_last;
    #pragma unroll
    for (int o = 32; o >= 1; o >>= 1) m0 = fmaxf(m0, __shfl_xor(m0, o));
    float logscale = m0 + cls;
    if (h == 0) w_lds[r] = expf(np_last - m0);
    __syncthreads();

    // prefetch B_{K-1}
    float bv[16];
    {
        const float* Brow = Bg + ((size_t)n * KCH + (KCH - 1)) * (C_ * C_) + r * C_ + h * 16;
        #pragma unroll
        for (int t = 0; t < 4; ++t) *(float4*)&bv[t * 4] = *(const float4*)(Brow + t * 4);
    }

    float sn = 0.f;
    for (int k = KCH - 1; k >= 0; --k) {
        float cb[16];
        #pragma unroll
        for (int t = 0; t < 16; ++t) cb[t] = bv[t];
        if (k > 0) {
            const float* Brow = Bg + ((size_t)n * KCH + (k - 1)) * (C_ * C_) + r * C_ + h * 16;
            #pragma unroll
            for (int t = 0; t < 4; ++t) *(float4*)&bv[t * 4] = *(const float4*)(Brow + t * 4);
        }
        float wv[16];
        #pragma unroll
        for (int t = 0; t < 4; ++t) *(float4*)&wv[t * 4] = *(const float4*)&w_lds[h * 16 + t * 4];
        float s = 0.f;
        #pragma unroll
        for (int t = 0; t < 16; ++t) s = fmaf(cb[t], wv[t], s);
        s += __shfl_xor(s, 32);   // combine halves -> full dot for row r

        float m = s;
        #pragma unroll
        for (int o = 16; o >= 1; o >>= 1) m = fmaxf(m, __shfl_xor(m, o));
        logscale += logf(m);
        sn = s / m;
        __syncthreads();
        if (h == 0) w_lds[r] = sn;
        __syncthreads();
    }

    float v = (h == 0) ? sn : 0.f;
    #pragma unroll
    for (int o = 32; o >= 1; o >>= 1) v += __shfl_xor(v, o);
    if (l == 0) logZ[n] = logf(v) + logscale;
}

// ---------------------------------------------------------------------------
// K4: per-(n, t-block) partial scores (deterministic: no atomics).
// ---------------------------------------------------------------------------
__global__ __launch_bounds__(256) void score_partial(const float* __restrict__ npots,
                                                     const float* __restrict__ labels,
                                                     const float* __restrict__ pad,
                                                     const float* __restrict__ T,
                                                     float* __restrict__ scores_p) {
    const int n = blockIdx.x, tb = blockIdx.y;
    const int tid = threadIdx.x;
    __shared__ int idx[65];
    const int tbase = tb * 64;

    for (int q = tid; q < 65 * C_; q += 256) {
        const int rl = q >> 5, c = q & 31;
        const int t = tbase - 1 + rl;
        if (t >= 0) {
            if (labels[((size_t)n * S_ + t) * C_ + c] > 0.5f) idx[rl] = c;
        }
    }
    __syncthreads();

    if (tid < 64) {
        const int t = tbase + tid;
        const float p = pad[(size_t)n * S_ + t];
        const int ct = idx[tid + 1];
        float v = p * npots[((size_t)n * S_ + t) * C_ + ct];
        if (t >= 1) v = fmaf(p, T[idx[tid] * C_ + ct], v);
        #pragma unroll
        for (int o = 32; o >= 1; o >>= 1) v += __shfl_xor(v, o);
        if (tid == 0) scores_p[n * 8 + tb] = v;
    }
}

// ---------------------------------------------------------------------------
// K5: loss = -mean(score - logZ)
// ---------------------------------------------------------------------------
__global__ __launch_bounds__(64) void finalize(const float* __restrict__ scores_p,
                                               const float* __restrict__ logZ,
                                               float* __restrict__ out) {
    const int l = threadIdx.x;
    float sc = 0.f;
    #pragma unroll
    for (int tb = 0; tb < 8; ++tb) sc += scores_p[l * 8 + tb];
    float v = sc - logZ[l];
    #pragma unroll
    for (int o = 32; o >= 1; o >>= 1) v += __shfl_xor(v, o);
    if (l == 0) out[0] = -v / (float)N_;
}

// ---------------------------------------------------------------------------
extern "C" void kernel_launch(void* const* d_in, const int* in_sizes, int n_in,
                              void* d_out, int out_size, void* d_ws, size_t ws_size,
                              hipStream_t stream) {
    const float* X      = (const float*)d_in[0];
    const float* W      = (const float*)d_in[1];
    const float* T      = (const float*)d_in[2];
    const float* labels = (const float*)d_in[3];
    const float* pad    = (const float*)d_in[4];
    float* out = (float*)d_out;

    float* npots    = (float*)d_ws;                       // 1,048,576 f
    float* Bg       = npots + (size_t)N_ * S_ * C_;       // 1,048,576 f
    float* chunk_ls = Bg + (size_t)N_ * KCH * C_ * C_;    // 1024 f
    float* logZ     = chunk_ls + N_ * KCH;                // 64 f
    float* scores_p = logZ + N_;                          // 512 f

    gemm_npots<<<(N_ * S_) / 128, 512, 0, stream>>>(X, W, npots);
    chunk_products<<<dim3(N_, KCH), 64, 0, stream>>>(npots, pad, T, Bg, chunk_ls);
    combine_logZ<<<N_, 64, 0, stream>>>(npots, pad, Bg, chunk_ls, logZ);
    score_partial<<<dim3(N_, 8), 256, 0, stream>>>(npots, labels, pad, T, scores_p);
    finalize<<<1, 64, 0, stream>>>(scores_p, logZ, out);
}

// Round 3
// 100.535 us; speedup vs baseline: 2.3212x; 1.2660x over previous
//
#include <hip/hip_runtime.h>
#include <hip/hip_bf16.h>
#include <math.h>

#define N_ 64
#define S_ 512
#define D_ 768
#define C_ 32
#define KCH 16    // chunks per sequence
#define LC 32     // steps per chunk

// ---------------------------------------------------------------------------
// K1: npots = X @ W. 128-row x 32-col tile, 512 threads, k-chunk 32.
// Per thread: 2 rows (ra, ra+64) x 4 cols (4jq..4jq+3).  (unchanged r2)
// ---------------------------------------------------------------------------
__global__ __launch_bounds__(512) void gemm_npots(const float* __restrict__ X,
                                                  const float* __restrict__ W,
                                                  float* __restrict__ npots) {
    __shared__ float Xs[128][36];
    __shared__ float Ws[32][36];
    const int tid  = threadIdx.x;
    const int row0 = blockIdx.x * 128;
    const int f  = tid & 7;
    const int rl = tid >> 3;
    const int kw = tid >> 4;
    const int c2 = tid & 15;
    const int ra = tid >> 3;
    const int jq = tid & 7;

    float acc[2][4] = {};

    for (int k0 = 0; k0 < D_; k0 += 32) {
        {
            const float4 v0 = *(const float4*)(X + (size_t)(row0 + rl) * D_ + k0 + f * 4);
            const float4 v1 = *(const float4*)(X + (size_t)(row0 + rl + 64) * D_ + k0 + f * 4);
            *(float4*)&Xs[rl][f * 4]      = v0;
            *(float4*)&Xs[rl + 64][f * 4] = v1;
        }
        {
            const float2 w = *(const float2*)(W + (size_t)(k0 + kw) * C_ + c2 * 2);
            Ws[kw][c2 * 2]     = w.x;
            Ws[kw][c2 * 2 + 1] = w.y;
        }
        __syncthreads();
        #pragma unroll
        for (int kk = 0; kk < 32; kk += 4) {
            float x0[4], x1[4], wv[4][4];
            *(float4*)x0 = *(const float4*)&Xs[ra][kk];
            *(float4*)x1 = *(const float4*)&Xs[ra + 64][kk];
            #pragma unroll
            for (int t = 0; t < 4; ++t) *(float4*)wv[t] = *(const float4*)&Ws[kk + t][jq * 4];
            #pragma unroll
            for (int t = 0; t < 4; ++t) {
                #pragma unroll
                for (int b = 0; b < 4; ++b) {
                    acc[0][b] = fmaf(x0[t], wv[t][b], acc[0][b]);
                    acc[1][b] = fmaf(x1[t], wv[t][b], acc[1][b]);
                }
            }
        }
        __syncthreads();
    }
    #pragma unroll
    for (int i = 0; i < 2; ++i) {
        const float4 o = make_float4(acc[i][0], acc[i][1], acc[i][2], acc[i][3]);
        *(float4*)(npots + (size_t)(row0 + ra + 64 * i) * C_ + jq * 4) = o;
    }
}

// ---------------------------------------------------------------------------
// K2: per-chunk 32x32 products of G_i = diag(e_i)*ET, i descending.
// Block (n,k), 256 threads (4 waves). Thread: row r=tid&31, cols 4g..4g+3.
// B double-buffered in LDS; 1 barrier/step; renorm (block reduce) every 8.
// ---------------------------------------------------------------------------
__global__ __launch_bounds__(256) void chunk_products(const float* __restrict__ npots,
                                                      const float* __restrict__ pad,
                                                      const float* __restrict__ T,
                                                      float* __restrict__ Bg,
                                                      float* __restrict__ chunk_ls) {
    const int n = blockIdx.x;
    const int k = blockIdx.y;
    const int tid = threadIdx.x;
    const int r = tid & 31;
    const int g = tid >> 5;          // 0..7 (cols 4g..4g+3)
    __shared__ float Bs[2][C_][36];
    __shared__ float e_lds[LC * C_];
    __shared__ float red[4];

    // sequence length (block-wide)
    const float* pm = pad + (size_t)n * S_;
    float ls = 0.f;
    for (int t = tid; t < S_; t += 256) ls += pm[t];
    #pragma unroll
    for (int o = 32; o >= 1; o >>= 1) ls += __shfl_xor(ls, o);
    if ((tid & 63) == 0) red[tid >> 6] = ls;
    __syncthreads();
    const int len = (int)(red[0] + red[1] + red[2] + red[3] + 0.5f);

    float* Bout = Bg + ((size_t)n * KCH + k) * (C_ * C_);
    const int lo = k * LC;
    const int hi = min(lo + LC, len - 1);

    if (lo >= len - 1) {   // empty chunk -> identity
        const float4 v = make_float4(r == 4 * g ? 1.f : 0.f,
                                     r == 4 * g + 1 ? 1.f : 0.f,
                                     r == 4 * g + 2 ? 1.f : 0.f,
                                     r == 4 * g + 3 ? 1.f : 0.f);
        *(float4*)(Bout + r * C_ + 4 * g) = v;
        if (tid == 0) chunk_ls[n * KCH + k] = 0.f;
        return;
    }

    // ET row r (32 regs, static)
    float ETr[C_];
    #pragma unroll
    for (int c = 0; c < C_; ++c) ETr[c] = expf(T[r * C_ + c]);

    // stage e = exp(npots) rows lo..hi-1
    const int cnt = hi - lo;
    const float* npn = npots + ((size_t)n * S_ + lo) * C_;
    for (int q = tid * 4; q < cnt * C_; q += 1024) {
        float4 v = *(const float4*)(npn + q);
        v.x = expf(v.x); v.y = expf(v.y); v.z = expf(v.z); v.w = expf(v.w);
        *(float4*)&e_lds[q] = v;
    }
    __syncthreads();

    // init B = G_{hi-1} = diag(e_{hi-1}) * ET
    float acc[4];
    {
        const float er = e_lds[(cnt - 1) * C_ + r];
        #pragma unroll
        for (int b = 0; b < 4; ++b) acc[b] = er * ETr[4 * g + b];
    }

    float logscale = 0.f;
    int p = 0;
    *(float4*)&Bs[0][r][4 * g] = make_float4(acc[0], acc[1], acc[2], acc[3]);
    __syncthreads();

    int it = 0;
    for (int i = hi - 2; i >= lo; --i) {
        float nacc[4] = {};
        #pragma unroll
        for (int c = 0; c < C_; ++c) {
            float bv[4];
            *(float4*)bv = *(const float4*)&Bs[p][c][4 * g];
            const float et = ETr[c];
            #pragma unroll
            for (int b = 0; b < 4; ++b) nacc[b] = fmaf(et, bv[b], nacc[b]);
        }
        const float er = e_lds[(i - lo) * C_ + r];
        #pragma unroll
        for (int b = 0; b < 4; ++b) acc[b] = er * nacc[b];

        if ((++it & 7) == 0) {   // block-wide renorm every 8 steps
            float m = fmaxf(fmaxf(acc[0], acc[1]), fmaxf(acc[2], acc[3]));
            #pragma unroll
            for (int o = 32; o >= 1; o >>= 1) m = fmaxf(m, __shfl_xor(m, o));
            if ((tid & 63) == 0) red[tid >> 6] = m;
            __syncthreads();
            m = fmaxf(fmaxf(red[0], red[1]), fmaxf(red[2], red[3]));
            logscale += logf(m);
            const float inv = 1.f / m;
            #pragma unroll
            for (int b = 0; b < 4; ++b) acc[b] *= inv;
        }

        *(float4*)&Bs[p ^ 1][r][4 * g] = make_float4(acc[0], acc[1], acc[2], acc[3]);
        __syncthreads();
        p ^= 1;
    }

    // final renorm + store
    {
        float m = fmaxf(fmaxf(acc[0], acc[1]), fmaxf(acc[2], acc[3]));
        #pragma unroll
        for (int o = 32; o >= 1; o >>= 1) m = fmaxf(m, __shfl_xor(m, o));
        if ((tid & 63) == 0) red[tid >> 6] = m;
        __syncthreads();
        m = fmaxf(fmaxf(red[0], red[1]), fmaxf(red[2], red[3]));
        logscale += logf(m);
        const float inv = 1.f / m;
        const float4 v = make_float4(acc[0] * inv, acc[1] * inv, acc[2] * inv, acc[3] * inv);
        *(float4*)(Bout + r * C_ + 4 * g) = v;
    }
    if (tid == 0) chunk_ls[n * KCH + k] = logscale;
}

// ---------------------------------------------------------------------------
// K3: apply B_{K-1}..B_0 to e_{len-1}; logZ = log(sum w) + logscales.
// One wave per n. Lane (r=l&31, h=l>>5).  (unchanged r2)
// ---------------------------------------------------------------------------
__global__ __launch_bounds__(64) void combine_logZ(const float* __restrict__ npots,
                                                   const float* __restrict__ pad,
                                                   const float* __restrict__ Bg,
                                                   const float* __restrict__ chunk_ls,
                                                   float* __restrict__ logZ) {
    const int n = blockIdx.x;
    const int l = threadIdx.x;
    const int r = l & 31;
    const int h = l >> 5;
    __shared__ __align__(16) float w_lds[32];

    const float* pm = pad + (size_t)n * S_;
    float ls = 0.f;
    for (int t = l; t < S_; t += 64) ls += pm[t];
    #pragma unroll
    for (int o = 32; o >= 1; o >>= 1) ls += __shfl_xor(ls, o);
    const int len = (int)(ls + 0.5f);

    float cls = (l < KCH) ? chunk_ls[n * KCH + l] : 0.f;
    #pragma unroll
    for (int o = 32; o >= 1; o >>= 1) cls += __shfl_xor(cls, o);

    const float np_last = npots[((size_t)n * S_ + (len - 1)) * C_ + r];
    float m0 = np_last;
    #pragma unroll
    for (int o = 32; o >= 1; o >>= 1) m0 = fmaxf(m0, __shfl_xor(m0, o));
    float logscale = m0 + cls;
    if (h == 0) w_lds[r] = expf(np_last - m0);
    __syncthreads();

    float bv[16];
    {
        const float* Brow = Bg + ((size_t)n * KCH + (KCH - 1)) * (C_ * C_) + r * C_ + h * 16;
        #pragma unroll
        for (int t = 0; t < 4; ++t) *(float4*)&bv[t * 4] = *(const float4*)(Brow + t * 4);
    }

    float sn = 0.f;
    for (int k = KCH - 1; k >= 0; --k) {
        float cb[16];
        #pragma unroll
        for (int t = 0; t < 16; ++t) cb[t] = bv[t];
        if (k > 0) {
            const float* Brow = Bg + ((size_t)n * KCH + (k - 1)) * (C_ * C_) + r * C_ + h * 16;
            #pragma unroll
            for (int t = 0; t < 4; ++t) *(float4*)&bv[t * 4] = *(const float4*)(Brow + t * 4);
        }
        float wv[16];
        #pragma unroll
        for (int t = 0; t < 4; ++t) *(float4*)&wv[t * 4] = *(const float4*)&w_lds[h * 16 + t * 4];
        float s = 0.f;
        #pragma unroll
        for (int t = 0; t < 16; ++t) s = fmaf(cb[t], wv[t], s);
        s += __shfl_xor(s, 32);

        float m = s;
        #pragma unroll
        for (int o = 16; o >= 1; o >>= 1) m = fmaxf(m, __shfl_xor(m, o));
        logscale += logf(m);
        sn = s / m;
        __syncthreads();
        if (h == 0) w_lds[r] = sn;
        __syncthreads();
    }

    float v = (h == 0) ? sn : 0.f;
    #pragma unroll
    for (int o = 32; o >= 1; o >>= 1) v += __shfl_xor(v, o);
    if (l == 0) logZ[n] = logf(v) + logscale;
}

// ---------------------------------------------------------------------------
// K4: per-(n, t-block) partial scores.  (unchanged r2)
// ---------------------------------------------------------------------------
__global__ __launch_bounds__(256) void score_partial(const float* __restrict__ npots,
                                                     const float* __restrict__ labels,
                                                     const float* __restrict__ pad,
                                                     const float* __restrict__ T,
                                                     float* __restrict__ scores_p) {
    const int n = blockIdx.x, tb = blockIdx.y;
    const int tid = threadIdx.x;
    __shared__ int idx[65];
    const int tbase = tb * 64;

    for (int q = tid; q < 65 * C_; q += 256) {
        const int rl = q >> 5, c = q & 31;
        const int t = tbase - 1 + rl;
        if (t >= 0) {
            if (labels[((size_t)n * S_ + t) * C_ + c] > 0.5f) idx[rl] = c;
        }
    }
    __syncthreads();

    if (tid < 64) {
        const int t = tbase + tid;
        const float p = pad[(size_t)n * S_ + t];
        const int ct = idx[tid + 1];
        float v = p * npots[((size_t)n * S_ + t) * C_ + ct];
        if (t >= 1) v = fmaf(p, T[idx[tid] * C_ + ct], v);
        #pragma unroll
        for (int o = 32; o >= 1; o >>= 1) v += __shfl_xor(v, o);
        if (tid == 0) scores_p[n * 8 + tb] = v;
    }
}

// ---------------------------------------------------------------------------
// K5: loss = -mean(score - logZ)
// ---------------------------------------------------------------------------
__global__ __launch_bounds__(64) void finalize(const float* __restrict__ scores_p,
                                               const float* __restrict__ logZ,
                                               float* __restrict__ out) {
    const int l = threadIdx.x;
    float sc = 0.f;
    #pragma unroll
    for (int tb = 0; tb < 8; ++tb) sc += scores_p[l * 8 + tb];
    float v = sc - logZ[l];
    #pragma unroll
    for (int o = 32; o >= 1; o >>= 1) v += __shfl_xor(v, o);
    if (l == 0) out[0] = -v / (float)N_;
}

// ---------------------------------------------------------------------------
extern "C" void kernel_launch(void* const* d_in, const int* in_sizes, int n_in,
                              void* d_out, int out_size, void* d_ws, size_t ws_size,
                              hipStream_t stream) {
    const float* X      = (const float*)d_in[0];
    const float* W      = (const float*)d_in[1];
    const float* T      = (const float*)d_in[2];
    const float* labels = (const float*)d_in[3];
    const float* pad    = (const float*)d_in[4];
    float* out = (float*)d_out;

    float* npots    = (float*)d_ws;                       // 1,048,576 f
    float* Bg       = npots + (size_t)N_ * S_ * C_;       // 1,048,576 f
    float* chunk_ls = Bg + (size_t)N_ * KCH * C_ * C_;    // 1024 f
    float* logZ     = chunk_ls + N_ * KCH;                // 64 f
    float* scores_p = logZ + N_;                          // 512 f

    gemm_npots<<<(N_ * S_) / 128, 512, 0, stream>>>(X, W, npots);
    chunk_products<<<dim3(N_, KCH), 256, 0, stream>>>(npots, pad, T, Bg, chunk_ls);
    combine_logZ<<<N_, 64, 0, stream>>>(npots, pad, Bg, chunk_ls, logZ);
    score_partial<<<dim3(N_, 8), 256, 0, stream>>>(npots, labels, pad, T, scores_p);
    finalize<<<1, 64, 0, stream>>>(scores_p, logZ, out);
}

// Round 4
// 89.240 us; speedup vs baseline: 2.6149x; 1.1266x over previous
//
#include <hip/hip_runtime.h>
#include <hip/hip_bf16.h>
#include <math.h>

#define N_ 64
#define S_ 512
#define D_ 768
#define C_ 32
#define KCH 16    // chunks per sequence
#define LC 32     // steps per chunk
#define WT_LD 776 // padded K stride for W^T (bf16)

typedef __attribute__((ext_vector_type(8))) short bf16x8;
typedef __attribute__((ext_vector_type(4))) float f32x4;

__device__ inline ushort f2bf(float x) {
    unsigned int b = __builtin_bit_cast(unsigned int, x);
    return (ushort)((b + 0x7FFFu + ((b >> 16) & 1u)) >> 16);   // RNE
}

// ---------------------------------------------------------------------------
// K0: Wt[c][k] = bf16(W[k][c]), c<32, k<768, row stride WT_LD.
// ---------------------------------------------------------------------------
__global__ __launch_bounds__(256) void wt_prep(const float* __restrict__ W,
                                               ushort* __restrict__ Wt) {
    const int idx = blockIdx.x * 256 + threadIdx.x;
    if (idx < D_ * C_) {
        const int k = idx >> 5, c = idx & 31;
        Wt[c * WT_LD + k] = f2bf(W[idx]);
    }
}

// ---------------------------------------------------------------------------
// K1: npots = X @ W via mfma_f32_16x16x32_bf16 (gemm_bt form, B = W^T).
// Block: 256 thr (4 waves), 64 rows. Wave: 16 rows x 32 cols, K=768.
// A-frag: global->reg f32 + cvt (row = lane&15, k = (lane>>4)*8 + j).
// B-frag: LDS W^T (col = lane&15 [+16], same k mapping).
// D: col = lane&15, row = (lane>>4)*4 + reg.   No barrier in K-loop.
// ---------------------------------------------------------------------------
__global__ __launch_bounds__(256) void gemm_npots_mfma(const float* __restrict__ X,
                                                       const ushort* __restrict__ Wt,
                                                       float* __restrict__ npots) {
    __shared__ ushort WtS[C_ * WT_LD];     // 49664 B
    const int tid = threadIdx.x;

    // stage W^T (contiguous copy, 3104 x 16B)
    {
        const uint4* src = (const uint4*)Wt;
        uint4* dst = (uint4*)WtS;
        for (int i = tid; i < (C_ * WT_LD) / 8; i += 256) dst[i] = src[i];
    }
    __syncthreads();

    const int wave = tid >> 6;
    const int l    = tid & 63;
    const int lr   = l & 15;
    const int lk   = (l >> 4) * 8;
    const int m0   = blockIdx.x * 64 + wave * 16;

    const float*  xrow = X + (size_t)(m0 + lr) * D_ + lk;
    const ushort* wb0  = &WtS[lr * WT_LD + lk];
    const ushort* wb1  = wb0 + 16 * WT_LD;

    f32x4 acc0 = {0.f, 0.f, 0.f, 0.f};
    f32x4 acc1 = {0.f, 0.f, 0.f, 0.f};

    #pragma unroll 4
    for (int k0 = 0; k0 < D_; k0 += 32) {
        const f32x4 alo = *(const f32x4*)(xrow + k0);
        const f32x4 ahi = *(const f32x4*)(xrow + k0 + 4);
        union { ushort u[8]; bf16x8 v; } af;
        #pragma unroll
        for (int j = 0; j < 4; ++j) {
            af.u[j]     = f2bf(alo[j]);
            af.u[4 + j] = f2bf(ahi[j]);
        }
        const bf16x8 b0 = *(const bf16x8*)(wb0 + k0);
        const bf16x8 b1 = *(const bf16x8*)(wb1 + k0);
        acc0 = __builtin_amdgcn_mfma_f32_16x16x32_bf16(af.v, b0, acc0, 0, 0, 0);
        acc1 = __builtin_amdgcn_mfma_f32_16x16x32_bf16(af.v, b1, acc1, 0, 0, 0);
    }

    const int r0 = m0 + ((l >> 4) << 2);
    #pragma unroll
    for (int reg = 0; reg < 4; ++reg) {
        npots[(size_t)(r0 + reg) * C_ + lr]      = acc0[reg];
        npots[(size_t)(r0 + reg) * C_ + lr + 16] = acc1[reg];
    }
}

// ---------------------------------------------------------------------------
// K2: per-chunk 32x32 products of G_i = diag(e_i)*ET, i descending.
// Block (n,k), 256 threads (4 waves). Thread: row r=tid&31, cols 4g..4g+3.
// (unchanged r3)
// ---------------------------------------------------------------------------
__global__ __launch_bounds__(256) void chunk_products(const float* __restrict__ npots,
                                                      const float* __restrict__ pad,
                                                      const float* __restrict__ T,
                                                      float* __restrict__ Bg,
                                                      float* __restrict__ chunk_ls) {
    const int n = blockIdx.x;
    const int k = blockIdx.y;
    const int tid = threadIdx.x;
    const int r = tid & 31;
    const int g = tid >> 5;
    __shared__ float Bs[2][C_][36];
    __shared__ float e_lds[LC * C_];
    __shared__ float red[4];

    const float* pm = pad + (size_t)n * S_;
    float ls = 0.f;
    for (int t = tid; t < S_; t += 256) ls += pm[t];
    #pragma unroll
    for (int o = 32; o >= 1; o >>= 1) ls += __shfl_xor(ls, o);
    if ((tid & 63) == 0) red[tid >> 6] = ls;
    __syncthreads();
    const int len = (int)(red[0] + red[1] + red[2] + red[3] + 0.5f);

    float* Bout = Bg + ((size_t)n * KCH + k) * (C_ * C_);
    const int lo = k * LC;
    const int hi = min(lo + LC, len - 1);

    if (lo >= len - 1) {
        const float4 v = make_float4(r == 4 * g ? 1.f : 0.f,
                                     r == 4 * g + 1 ? 1.f : 0.f,
                                     r == 4 * g + 2 ? 1.f : 0.f,
                                     r == 4 * g + 3 ? 1.f : 0.f);
        *(float4*)(Bout + r * C_ + 4 * g) = v;
        if (tid == 0) chunk_ls[n * KCH + k] = 0.f;
        return;
    }

    float ETr[C_];
    #pragma unroll
    for (int c = 0; c < C_; ++c) ETr[c] = expf(T[r * C_ + c]);

    const int cnt = hi - lo;
    const float* npn = npots + ((size_t)n * S_ + lo) * C_;
    for (int q = tid * 4; q < cnt * C_; q += 1024) {
        float4 v = *(const float4*)(npn + q);
        v.x = expf(v.x); v.y = expf(v.y); v.z = expf(v.z); v.w = expf(v.w);
        *(float4*)&e_lds[q] = v;
    }
    __syncthreads();

    float acc[4];
    {
        const float er = e_lds[(cnt - 1) * C_ + r];
        #pragma unroll
        for (int b = 0; b < 4; ++b) acc[b] = er * ETr[4 * g + b];
    }

    float logscale = 0.f;
    int p = 0;
    *(float4*)&Bs[0][r][4 * g] = make_float4(acc[0], acc[1], acc[2], acc[3]);
    __syncthreads();

    int it = 0;
    for (int i = hi - 2; i >= lo; --i) {
        float nacc[4] = {};
        #pragma unroll
        for (int c = 0; c < C_; ++c) {
            float bv[4];
            *(float4*)bv = *(const float4*)&Bs[p][c][4 * g];
            const float et = ETr[c];
            #pragma unroll
            for (int b = 0; b < 4; ++b) nacc[b] = fmaf(et, bv[b], nacc[b]);
        }
        const float er = e_lds[(i - lo) * C_ + r];
        #pragma unroll
        for (int b = 0; b < 4; ++b) acc[b] = er * nacc[b];

        if ((++it & 7) == 0) {
            float m = fmaxf(fmaxf(acc[0], acc[1]), fmaxf(acc[2], acc[3]));
            #pragma unroll
            for (int o = 32; o >= 1; o >>= 1) m = fmaxf(m, __shfl_xor(m, o));
            if ((tid & 63) == 0) red[tid >> 6] = m;
            __syncthreads();
            m = fmaxf(fmaxf(red[0], red[1]), fmaxf(red[2], red[3]));
            logscale += logf(m);
            const float inv = 1.f / m;
            #pragma unroll
            for (int b = 0; b < 4; ++b) acc[b] *= inv;
        }

        *(float4*)&Bs[p ^ 1][r][4 * g] = make_float4(acc[0], acc[1], acc[2], acc[3]);
        __syncthreads();
        p ^= 1;
    }

    {
        float m = fmaxf(fmaxf(acc[0], acc[1]), fmaxf(acc[2], acc[3]));
        #pragma unroll
        for (int o = 32; o >= 1; o >>= 1) m = fmaxf(m, __shfl_xor(m, o));
        if ((tid & 63) == 0) red[tid >> 6] = m;
        __syncthreads();
        m = fmaxf(fmaxf(red[0], red[1]), fmaxf(red[2], red[3]));
        logscale += logf(m);
        const float inv = 1.f / m;
        const float4 v = make_float4(acc[0] * inv, acc[1] * inv, acc[2] * inv, acc[3] * inv);
        *(float4*)(Bout + r * C_ + 4 * g) = v;
    }
    if (tid == 0) chunk_ls[n * KCH + k] = logscale;
}

// ---------------------------------------------------------------------------
// K3: apply B_{K-1}..B_0 to e_{len-1}; logZ. One wave per n. (unchanged)
// ---------------------------------------------------------------------------
__global__ __launch_bounds__(64) void combine_logZ(const float* __restrict__ npots,
                                                   const float* __restrict__ pad,
                                                   const float* __restrict__ Bg,
                                                   const float* __restrict__ chunk_ls,
                                                   float* __restrict__ logZ) {
    const int n = blockIdx.x;
    const int l = threadIdx.x;
    const int r = l & 31;
    const int h = l >> 5;
    __shared__ __align__(16) float w_lds[32];

    const float* pm = pad + (size_t)n * S_;
    float ls = 0.f;
    for (int t = l; t < S_; t += 64) ls += pm[t];
    #pragma unroll
    for (int o = 32; o >= 1; o >>= 1) ls += __shfl_xor(ls, o);
    const int len = (int)(ls + 0.5f);

    float cls = (l < KCH) ? chunk_ls[n * KCH + l] : 0.f;
    #pragma unroll
    for (int o = 32; o >= 1; o >>= 1) cls += __shfl_xor(cls, o);

    const float np_last = npots[((size_t)n * S_ + (len - 1)) * C_ + r];
    float m0 = np_last;
    #pragma unroll
    for (int o = 32; o >= 1; o >>= 1) m0 = fmaxf(m0, __shfl_xor(m0, o));
    float logscale = m0 + cls;
    if (h == 0) w_lds[r] = expf(np_last - m0);
    __syncthreads();

    float bv[16];
    {
        const float* Brow = Bg + ((size_t)n * KCH + (KCH - 1)) * (C_ * C_) + r * C_ + h * 16;
        #pragma unroll
        for (int t = 0; t < 4; ++t) *(float4*)&bv[t * 4] = *(const float4*)(Brow + t * 4);
    }

    float sn = 0.f;
    for (int k = KCH - 1; k >= 0; --k) {
        float cb[16];
        #pragma unroll
        for (int t = 0; t < 16; ++t) cb[t] = bv[t];
        if (k > 0) {
            const float* Brow = Bg + ((size_t)n * KCH + (k - 1)) * (C_ * C_) + r * C_ + h * 16;
            #pragma unroll
            for (int t = 0; t < 4; ++t) *(float4*)&bv[t * 4] = *(const float4*)(Brow + t * 4);
        }
        float wv[16];
        #pragma unroll
        for (int t = 0; t < 4; ++t) *(float4*)&wv[t * 4] = *(const float4*)&w_lds[h * 16 + t * 4];
        float s = 0.f;
        #pragma unroll
        for (int t = 0; t < 16; ++t) s = fmaf(cb[t], wv[t], s);
        s += __shfl_xor(s, 32);

        float m = s;
        #pragma unroll
        for (int o = 16; o >= 1; o >>= 1) m = fmaxf(m, __shfl_xor(m, o));
        logscale += logf(m);
        sn = s / m;
        __syncthreads();
        if (h == 0) w_lds[r] = sn;
        __syncthreads();
    }

    float v = (h == 0) ? sn : 0.f;
    #pragma unroll
    for (int o = 32; o >= 1; o >>= 1) v += __shfl_xor(v, o);
    if (l == 0) logZ[n] = logf(v) + logscale;
}

// ---------------------------------------------------------------------------
// K4: per-(n, t-block) partial scores. (unchanged)
// ---------------------------------------------------------------------------
__global__ __launch_bounds__(256) void score_partial(const float* __restrict__ npots,
                                                     const float* __restrict__ labels,
                                                     const float* __restrict__ pad,
                                                     const float* __restrict__ T,
                                                     float* __restrict__ scores_p) {
    const int n = blockIdx.x, tb = blockIdx.y;
    const int tid = threadIdx.x;
    __shared__ int idx[65];
    const int tbase = tb * 64;

    for (int q = tid; q < 65 * C_; q += 256) {
        const int rl = q >> 5, c = q & 31;
        const int t = tbase - 1 + rl;
        if (t >= 0) {
            if (labels[((size_t)n * S_ + t) * C_ + c] > 0.5f) idx[rl] = c;
        }
    }
    __syncthreads();

    if (tid < 64) {
        const int t = tbase + tid;
        const float p = pad[(size_t)n * S_ + t];
        const int ct = idx[tid + 1];
        float v = p * npots[((size_t)n * S_ + t) * C_ + ct];
        if (t >= 1) v = fmaf(p, T[idx[tid] * C_ + ct], v);
        #pragma unroll
        for (int o = 32; o >= 1; o >>= 1) v += __shfl_xor(v, o);
        if (tid == 0) scores_p[n * 8 + tb] = v;
    }
}

// ---------------------------------------------------------------------------
// K5: loss = -mean(score - logZ)
// ---------------------------------------------------------------------------
__global__ __launch_bounds__(64) void finalize(const float* __restrict__ scores_p,
                                               const float* __restrict__ logZ,
                                               float* __restrict__ out) {
    const int l = threadIdx.x;
    float sc = 0.f;
    #pragma unroll
    for (int tb = 0; tb < 8; ++tb) sc += scores_p[l * 8 + tb];
    float v = sc - logZ[l];
    #pragma unroll
    for (int o = 32; o >= 1; o >>= 1) v += __shfl_xor(v, o);
    if (l == 0) out[0] = -v / (float)N_;
}

// ---------------------------------------------------------------------------
extern "C" void kernel_launch(void* const* d_in, const int* in_sizes, int n_in,
                              void* d_out, int out_size, void* d_ws, size_t ws_size,
                              hipStream_t stream) {
    const float* X      = (const float*)d_in[0];
    const float* W      = (const float*)d_in[1];
    const float* T      = (const float*)d_in[2];
    const float* labels = (const float*)d_in[3];
    const float* pad    = (const float*)d_in[4];
    float* out = (float*)d_out;

    float* npots    = (float*)d_ws;                       // 1,048,576 f
    float* Bg       = npots + (size_t)N_ * S_ * C_;       // 1,048,576 f
    float* chunk_ls = Bg + (size_t)N_ * KCH * C_ * C_;    // 1024 f
    float* logZ     = chunk_ls + N_ * KCH;                // 64 f
    float* scores_p = logZ + N_;                          // 512 f
    ushort* Wt      = (ushort*)(scores_p + 512);          // 32*776 bf16 (16B-aligned)

    wt_prep<<<96, 256, 0, stream>>>(W, Wt);
    gemm_npots_mfma<<<(N_ * S_) / 64, 256, 0, stream>>>(X, Wt, npots);
    chunk_products<<<dim3(N_, KCH), 256, 0, stream>>>(npots, pad, T, Bg, chunk_ls);
    combine_logZ<<<N_, 64, 0, stream>>>(npots, pad, Bg, chunk_ls, logZ);
    score_partial<<<dim3(N_, 8), 256, 0, stream>>>(npots, labels, pad, T, scores_p);
    finalize<<<1, 64, 0, stream>>>(scores_p, logZ, out);
}

// Round 5
// 54.352 us; speedup vs baseline: 4.2935x; 1.6419x over previous
//
#include <hip/hip_runtime.h>
#include <hip/hip_bf16.h>
#include <math.h>

#define N_ 64
#define S_ 512
#define D_ 768
#define C_ 32
#define KCH 16    // chunks per sequence
#define LC 32     // steps per chunk
#define WT_LD 776 // padded K stride for W^T (bf16)

typedef __attribute__((ext_vector_type(8))) short bf16x8;
typedef __attribute__((ext_vector_type(4))) float f32x4;
typedef __attribute__((ext_vector_type(16))) float f32x16;

__device__ inline ushort f2bf(float x) {
    unsigned int b = __builtin_bit_cast(unsigned int, x);
    return (ushort)((b + 0x7FFFu + ((b >> 16) & 1u)) >> 16);   // RNE
}

__device__ inline unsigned cvt_pk_bf16(float lo, float hi) {   // D[15:0]=bf16(lo), D[31:16]=bf16(hi)
    unsigned r;
    asm("v_cvt_pk_bf16_f32 %0, %1, %2" : "=v"(r) : "v"(lo), "v"(hi));
    return r;
}

// ---------------------------------------------------------------------------
// K0: Wt[c][k] = bf16(W[k][c])
// ---------------------------------------------------------------------------
__global__ __launch_bounds__(256) void wt_prep(const float* __restrict__ W,
                                               ushort* __restrict__ Wt) {
    const int idx = blockIdx.x * 256 + threadIdx.x;
    if (idx < D_ * C_) {
        const int k = idx >> 5, c = idx & 31;
        Wt[c * WT_LD + k] = f2bf(W[idx]);
    }
}

// ---------------------------------------------------------------------------
// K1: npots = X @ W via mfma_f32_16x16x32_bf16. No LDS, no barriers.
// Wave: 16 rows x 32 cols. A: global f32 -> cvt_pk bf16. B: W^T from L2.
// ---------------------------------------------------------------------------
__global__ __launch_bounds__(256) void gemm_npots_mfma(const float* __restrict__ X,
                                                       const ushort* __restrict__ Wt,
                                                       float* __restrict__ npots) {
    const int tid = threadIdx.x;
    const int wave = tid >> 6;
    const int l    = tid & 63;
    const int lr   = l & 15;
    const int lk   = (l >> 4) * 8;
    const int m0   = blockIdx.x * 64 + wave * 16;

    const float*  xrow = X + (size_t)(m0 + lr) * D_ + lk;
    const ushort* wb0  = Wt + lr * WT_LD + lk;
    const ushort* wb1  = wb0 + 16 * WT_LD;

    f32x4 acc0 = {0.f, 0.f, 0.f, 0.f};
    f32x4 acc1 = {0.f, 0.f, 0.f, 0.f};

    #pragma unroll 4
    for (int k0 = 0; k0 < D_; k0 += 32) {
        const f32x4 alo = *(const f32x4*)(xrow + k0);
        const f32x4 ahi = *(const f32x4*)(xrow + k0 + 4);
        union { unsigned w[4]; bf16x8 v; } af;
        af.w[0] = cvt_pk_bf16(alo[0], alo[1]);
        af.w[1] = cvt_pk_bf16(alo[2], alo[3]);
        af.w[2] = cvt_pk_bf16(ahi[0], ahi[1]);
        af.w[3] = cvt_pk_bf16(ahi[2], ahi[3]);
        const bf16x8 b0 = *(const bf16x8*)(wb0 + k0);
        const bf16x8 b1 = *(const bf16x8*)(wb1 + k0);
        acc0 = __builtin_amdgcn_mfma_f32_16x16x32_bf16(af.v, b0, acc0, 0, 0, 0);
        acc1 = __builtin_amdgcn_mfma_f32_16x16x32_bf16(af.v, b1, acc1, 0, 0, 0);
    }

    const int r0 = m0 + ((l >> 4) << 2);
    #pragma unroll
    for (int reg = 0; reg < 4; ++reg) {
        npots[(size_t)(r0 + reg) * C_ + lr]      = acc0[reg];
        npots[(size_t)(r0 + reg) * C_ + lr + 16] = acc1[reg];
    }
}

// ---------------------------------------------------------------------------
// K2: block (n,k), 128 thr. Wave0: chunk 32x32 product via MFMA.
//     Wave1: score partial for window [32k, 32k+32). No barriers at all.
// Wave0 math: B_new = diag(e_i) * (ET * B_old), i descending; MFMA A=ET
// (bf16, resident), B=B_old (bf16, recycled in-register each step).
// D layout: col=lane&31, row=(reg&3)+8*(reg>>2)+4*(lane>>5)  [m74/m101].
// A/B layout: row|col=lane&31, k=(lane>>5)*8+j.
// ---------------------------------------------------------------------------
__global__ __launch_bounds__(128) void chunk_score(const float* __restrict__ npots,
                                                   const float* __restrict__ pad,
                                                   const float* __restrict__ T,
                                                   const float* __restrict__ labels,
                                                   float* __restrict__ Bg,
                                                   float* __restrict__ chunk_ls,
                                                   float* __restrict__ scores_p) {
    const int n = blockIdx.x, k = blockIdx.y;
    const int tid = threadIdx.x;
    const int l = tid & 63;
    __shared__ __align__(16) float e_lds[LC * C_];

    if (tid >= 64) {
        // ---------------- wave 1: score partial (shfl-only, no LDS) --------
        const int tb = k * LC;
        int best = 0;
        if (l <= LC) {
            const int t = tb - 1 + l;
            if (t >= 0) {
                const float* lrow = labels + ((size_t)n * S_ + t) * C_;
                float bv = lrow[0];
                #pragma unroll
                for (int c = 1; c < C_; ++c) {
                    const float x = lrow[c];
                    if (x > bv) { bv = x; best = c; }
                }
            }
        }
        const int cur = __shfl(best, l + 1);   // idx[t], own best = idx[t-1]
        float v = 0.f;
        if (l < LC) {
            const int t = tb + l;
            const float p = pad[(size_t)n * S_ + t];
            v = p * npots[((size_t)n * S_ + t) * C_ + cur];
            if (t >= 1) v = fmaf(p, T[best * C_ + cur], v);
        }
        #pragma unroll
        for (int o = 32; o >= 1; o >>= 1) v += __shfl_xor(v, o);
        if (l == 0) scores_p[n * KCH + k] = v;
        return;
    }

    // ---------------- wave 0: chunk matrix product ----------------
    const int cc = l & 31;     // D col / A row / B col
    const int h  = l >> 5;

    const float* pm = pad + (size_t)n * S_;
    float ls = 0.f;
    for (int t = l; t < S_; t += 64) ls += pm[t];
    #pragma unroll
    for (int o = 32; o >= 1; o >>= 1) ls += __shfl_xor(ls, o);
    const int len = (int)(ls + 0.5f);

    float* Bout = Bg + ((size_t)n * KCH + k) * (C_ * C_);
    const int lo = k * LC;
    const int hi = min(lo + LC, len - 1);

    if (lo >= len - 1) {   // empty chunk -> identity
        #pragma unroll
        for (int q = 0; q < 16; ++q) {
            const int row = (q & 3) + 8 * (q >> 2) + 4 * h;
            Bout[row * C_ + cc] = (row == cc) ? 1.f : 0.f;
        }
        if (l == 0) chunk_ls[n * KCH + k] = 0.f;
        return;
    }

    const int cnt = hi - lo;

    // stage e = exp(npots[lo..hi-1]) into LDS
    const float* npn = npots + ((size_t)n * S_ + lo) * C_;
    for (int q = l * 4; q < cnt * C_; q += 256) {
        const float4 v = *(const float4*)(npn + q);
        *(float4*)&e_lds[q] = make_float4(expf(v.x), expf(v.y), expf(v.z), expf(v.w));
    }
    asm volatile("s_waitcnt lgkmcnt(0)" ::: "memory");   // cross-lane LDS visibility (single wave)

    // init B-op = G_{hi-1}:  G(kk,cc) = e_last[kk] * ET(kk,cc)
    float glo[8], ghi[8];
    {
        const float* el = e_lds + (size_t)(cnt - 1) * C_;
        #pragma unroll
        for (int j = 0; j < 8; ++j) {
            const int kk = 8 * h + j;
            glo[j] = el[kk]      * expf(T[kk * C_ + cc]);
            ghi[j] = el[kk + 16] * expf(T[(kk + 16) * C_ + cc]);
        }
    }

    if (cnt == 1) {    // single-step chunk: store G directly (f32)
        #pragma unroll
        for (int j = 0; j < 8; ++j) {
            Bout[(8 * h + j) * C_ + cc]      = glo[j];
            Bout[(8 * h + j + 16) * C_ + cc] = ghi[j];
        }
        if (l == 0) chunk_ls[n * KCH + k] = 0.f;
        return;
    }

    // resident ET A-fragments: A(row=cc, k=8h+j) and +16
    union { unsigned w[4]; bf16x8 v; } ETalo, ETahi, blo, bhi;
    #pragma unroll
    for (int t = 0; t < 4; ++t) {
        const int kk = 8 * h + 2 * t;
        ETalo.w[t] = cvt_pk_bf16(expf(T[cc * C_ + kk]),      expf(T[cc * C_ + kk + 1]));
        ETahi.w[t] = cvt_pk_bf16(expf(T[cc * C_ + kk + 16]), expf(T[cc * C_ + kk + 17]));
        blo.w[t]   = cvt_pk_bf16(glo[2 * t], glo[2 * t + 1]);
        bhi.w[t]   = cvt_pk_bf16(ghi[2 * t], ghi[2 * t + 1]);
    }

    float logscale = 0.f;
    int it = 0;
    for (int i = hi - 2; i >= lo; --i) {
        f32x16 d = {};
        d = __builtin_amdgcn_mfma_f32_32x32x16_bf16(ETalo.v, blo.v, d, 0, 0, 0);
        d = __builtin_amdgcn_mfma_f32_32x32x16_bf16(ETahi.v, bhi.v, d, 0, 0, 0);

        // row scaling: rows (reg&3)+8*(reg>>2)+4h  -> 4 broadcast float4 reads
        const float* ep = e_lds + (i - lo) * C_ + 4 * h;
        const float4 e0 = *(const float4*)(ep);
        const float4 e1 = *(const float4*)(ep + 8);
        const float4 e2 = *(const float4*)(ep + 16);
        const float4 e3 = *(const float4*)(ep + 24);
        float sd[16];
        sd[0]  = d[0]  * e0.x;  sd[1]  = d[1]  * e0.y;  sd[2]  = d[2]  * e0.z;  sd[3]  = d[3]  * e0.w;
        sd[4]  = d[4]  * e1.x;  sd[5]  = d[5]  * e1.y;  sd[6]  = d[6]  * e1.z;  sd[7]  = d[7]  * e1.w;
        sd[8]  = d[8]  * e2.x;  sd[9]  = d[9]  * e2.y;  sd[10] = d[10] * e2.z;  sd[11] = d[11] * e2.w;
        sd[12] = d[12] * e3.x;  sd[13] = d[13] * e3.y;  sd[14] = d[14] * e3.z;  sd[15] = d[15] * e3.w;

        if ((++it & 7) == 0) {   // renorm every 8 steps
            float m = sd[0];
            #pragma unroll
            for (int q = 1; q < 16; ++q) m = fmaxf(m, sd[q]);
            #pragma unroll
            for (int o = 32; o >= 1; o >>= 1) m = fmaxf(m, __shfl_xor(m, o));
            logscale += logf(m);
            const float inv = 1.f / m;
            #pragma unroll
            for (int q = 0; q < 16; ++q) sd[q] *= inv;
        }

        if (i > lo) {
            // D -> next B-operand: cvt_pk pairs + half-exchange via shfl_xor(32)
            const unsigned w0 = cvt_pk_bf16(sd[0],  sd[1]);
            const unsigned w1 = cvt_pk_bf16(sd[2],  sd[3]);
            const unsigned w2 = cvt_pk_bf16(sd[4],  sd[5]);
            const unsigned w3 = cvt_pk_bf16(sd[6],  sd[7]);
            const unsigned w4 = cvt_pk_bf16(sd[8],  sd[9]);
            const unsigned w5 = cvt_pk_bf16(sd[10], sd[11]);
            const unsigned w6 = cvt_pk_bf16(sd[12], sd[13]);
            const unsigned w7 = cvt_pk_bf16(sd[14], sd[15]);
            const unsigned x0 = (unsigned)__shfl_xor((int)w0, 32);
            const unsigned x1 = (unsigned)__shfl_xor((int)w1, 32);
            const unsigned x2 = (unsigned)__shfl_xor((int)w2, 32);
            const unsigned x3 = (unsigned)__shfl_xor((int)w3, 32);
            const unsigned x4 = (unsigned)__shfl_xor((int)w4, 32);
            const unsigned x5 = (unsigned)__shfl_xor((int)w5, 32);
            const unsigned x6 = (unsigned)__shfl_xor((int)w6, 32);
            const unsigned x7 = (unsigned)__shfl_xor((int)w7, 32);
            blo.w[0] = h ? x2 : w0;   // k pair (0,1) | (8,9)
            blo.w[1] = h ? x3 : w1;   // (2,3) | (10,11)
            blo.w[2] = h ? w2 : x0;   // (4,5) | (12,13)
            blo.w[3] = h ? w3 : x1;   // (6,7) | (14,15)
            bhi.w[0] = h ? x6 : w4;   // (16,17) | (24,25)
            bhi.w[1] = h ? x7 : w5;
            bhi.w[2] = h ? w6 : x4;
            bhi.w[3] = h ? w7 : x5;
        } else {
            #pragma unroll
            for (int q = 0; q < 16; ++q)
                Bout[((q & 3) + 8 * (q >> 2) + 4 * h) * C_ + cc] = sd[q];
        }
    }
    if (l == 0) chunk_ls[n * KCH + k] = logscale;
}

// ---------------------------------------------------------------------------
// K3: apply B_{K-1}..B_0 to e_{len-1}; logZ. One wave per n. (unchanged)
// ---------------------------------------------------------------------------
__global__ __launch_bounds__(64) void combine_logZ(const float* __restrict__ npots,
                                                   const float* __restrict__ pad,
                                                   const float* __restrict__ Bg,
                                                   const float* __restrict__ chunk_ls,
                                                   float* __restrict__ logZ) {
    const int n = blockIdx.x;
    const int l = threadIdx.x;
    const int r = l & 31;
    const int h = l >> 5;
    __shared__ __align__(16) float w_lds[32];

    const float* pm = pad + (size_t)n * S_;
    float ls = 0.f;
    for (int t = l; t < S_; t += 64) ls += pm[t];
    #pragma unroll
    for (int o = 32; o >= 1; o >>= 1) ls += __shfl_xor(ls, o);
    const int len = (int)(ls + 0.5f);

    float cls = (l < KCH) ? chunk_ls[n * KCH + l] : 0.f;
    #pragma unroll
    for (int o = 32; o >= 1; o >>= 1) cls += __shfl_xor(cls, o);

    const float np_last = npots[((size_t)n * S_ + (len - 1)) * C_ + r];
    float m0 = np_last;
    #pragma unroll
    for (int o = 32; o >= 1; o >>= 1) m0 = fmaxf(m0, __shfl_xor(m0, o));
    float logscale = m0 + cls;
    if (h == 0) w_lds[r] = expf(np_last - m0);
    __syncthreads();

    float bv[16];
    {
        const float* Brow = Bg + ((size_t)n * KCH + (KCH - 1)) * (C_ * C_) + r * C_ + h * 16;
        #pragma unroll
        for (int t = 0; t < 4; ++t) *(float4*)&bv[t * 4] = *(const float4*)(Brow + t * 4);
    }

    float sn = 0.f;
    for (int k = KCH - 1; k >= 0; --k) {
        float cb[16];
        #pragma unroll
        for (int t = 0; t < 16; ++t) cb[t] = bv[t];
        if (k > 0) {
            const float* Brow = Bg + ((size_t)n * KCH + (k - 1)) * (C_ * C_) + r * C_ + h * 16;
            #pragma unroll
            for (int t = 0; t < 4; ++t) *(float4*)&bv[t * 4] = *(const float4*)(Brow + t * 4);
        }
        float wv[16];
        #pragma unroll
        for (int t = 0; t < 4; ++t) *(float4*)&wv[t * 4] = *(const float4*)&w_lds[h * 16 + t * 4];
        float s = 0.f;
        #pragma unroll
        for (int t = 0; t < 16; ++t) s = fmaf(cb[t], wv[t], s);
        s += __shfl_xor(s, 32);

        float m = s;
        #pragma unroll
        for (int o = 16; o >= 1; o >>= 1) m = fmaxf(m, __shfl_xor(m, o));
        logscale += logf(m);
        sn = s / m;
        __syncthreads();
        if (h == 0) w_lds[r] = sn;
        __syncthreads();
    }

    float v = (h == 0) ? sn : 0.f;
    #pragma unroll
    for (int o = 32; o >= 1; o >>= 1) v += __shfl_xor(v, o);
    if (l == 0) logZ[n] = logf(v) + logscale;
}

// ---------------------------------------------------------------------------
// K4: loss = -mean(score - logZ); score_n = sum of 16 window partials
// ---------------------------------------------------------------------------
__global__ __launch_bounds__(64) void finalize(const float* __restrict__ scores_p,
                                               const float* __restrict__ logZ,
                                               float* __restrict__ out) {
    const int l = threadIdx.x;
    float sc = 0.f;
    #pragma unroll
    for (int tb = 0; tb < KCH; ++tb) sc += scores_p[l * KCH + tb];
    float v = sc - logZ[l];
    #pragma unroll
    for (int o = 32; o >= 1; o >>= 1) v += __shfl_xor(v, o);
    if (l == 0) out[0] = -v / (float)N_;
}

// ---------------------------------------------------------------------------
extern "C" void kernel_launch(void* const* d_in, const int* in_sizes, int n_in,
                              void* d_out, int out_size, void* d_ws, size_t ws_size,
                              hipStream_t stream) {
    const float* X      = (const float*)d_in[0];
    const float* W      = (const float*)d_in[1];
    const float* T      = (const float*)d_in[2];
    const float* labels = (const float*)d_in[3];
    const float* pad    = (const float*)d_in[4];
    float* out = (float*)d_out;

    float* npots    = (float*)d_ws;                       // 1,048,576 f
    float* Bg       = npots + (size_t)N_ * S_ * C_;       // 1,048,576 f
    float* chunk_ls = Bg + (size_t)N_ * KCH * C_ * C_;    // 1024 f
    float* logZ     = chunk_ls + N_ * KCH;                // 64 f
    float* scores_p = logZ + N_;                          // 1024 f
    ushort* Wt      = (ushort*)(scores_p + 1024);         // 32*776 bf16

    wt_prep<<<96, 256, 0, stream>>>(W, Wt);
    gemm_npots_mfma<<<(N_ * S_) / 64, 256, 0, stream>>>(X, Wt, npots);
    chunk_score<<<dim3(N_, KCH), 128, 0, stream>>>(npots, pad, T, labels, Bg, chunk_ls, scores_p);
    combine_logZ<<<N_, 64, 0, stream>>>(npots, pad, Bg, chunk_ls, logZ);
    finalize<<<1, 64, 0, stream>>>(scores_p, logZ, out);
}

// Round 6
// 49.858 us; speedup vs baseline: 4.6804x; 1.0901x over previous
//
#include <hip/hip_runtime.h>
#include <hip/hip_bf16.h>
#include <math.h>

#define N_ 64
#define S_ 512
#define D_ 768
#define C_ 32
#define KCH 16     // chunks per sequence (scan)
#define LC 32      // steps per chunk (scan)
#define WT_LD 776  // padded K stride for W^T (bf16)
#define BKC 96     // gemm K-chunk (floats)
#define ROWS_PB 128

typedef __attribute__((ext_vector_type(8))) short bf16x8;
typedef __attribute__((ext_vector_type(4))) float f32x4;
typedef __attribute__((ext_vector_type(16))) float f32x16;

__device__ inline ushort f2bf(float x) {
    unsigned int b = __builtin_bit_cast(unsigned int, x);
    return (ushort)((b + 0x7FFFu + ((b >> 16) & 1u)) >> 16);   // RNE
}

__device__ inline unsigned cvt_pk_bf16(float lo, float hi) {   // D[15:0]=bf16(lo), D[31:16]=bf16(hi)
    unsigned r;
    asm("v_cvt_pk_bf16_f32 %0, %1, %2" : "=v"(r) : "v"(lo), "v"(hi));
    return r;
}

__device__ __forceinline__ void gload_lds16(const float* g, float* l) {
    __builtin_amdgcn_global_load_lds(
        (const __attribute__((address_space(1))) unsigned int*)g,
        (__attribute__((address_space(3))) unsigned int*)l, 16, 0, 0);
}

// ---------------------------------------------------------------------------
// K1: npots = X @ W via mfma_f32_16x16x32_bf16.
// 256 blocks x 512 thr (8 waves), 128 rows/block, K staged in 96-float chunks
// via global_load_lds (double-buffered, 1 barrier/chunk). X tile XOR-swizzled
// (granule ^= row&7) on BOTH sides: pre-swizzled global source (gload_lds dest
// must stay linear) + swizzled ds_read. W transposed+cvt'd to bf16 LDS in-block.
// ---------------------------------------------------------------------------
__global__ __launch_bounds__(512) void gemm_npots_mfma(const float* __restrict__ X,
                                                       const float* __restrict__ W,
                                                       float* __restrict__ npots) {
    __shared__ float  Xs[2][ROWS_PB * BKC];   // 2 x 48 KiB
    __shared__ ushort WtS[C_ * WT_LD];        // 48.5 KiB
    const int tid = threadIdx.x;
    const int w   = tid >> 6;      // wave 0..7
    const int l   = tid & 63;
    const int lr  = l & 15;        // A row within 16-tile / B col
    const int q   = l >> 4;        // k-quarter: lk = 8q
    const int row0 = blockIdx.x * ROWS_PB;

    // --- build W^T bf16 in LDS (once per block) ---
    for (int i = tid; i < D_ * C_; i += 512) {
        const int k = i >> 5, c = i & 31;
        WtS[c * WT_LD + k] = f2bf(W[i]);
    }

    // --- staging helper: chunk ck -> buffer buf (6 x 1KiB per wave) ---
    // granule G in [0,3072): row = G/24, g = G%24; source granule g^(row&7).
    #define STAGE(ck, buf)                                                        \
        {                                                                         \
            _Pragma("unroll")                                                     \
            for (int i_ = 0; i_ < 6; ++i_) {                                      \
                const int G   = (w * 6 + i_) * 64 + l;                            \
                const int row = G / 24;                                           \
                const int g   = G - row * 24;                                     \
                const int gs  = g ^ (row & 7);                                    \
                gload_lds16(X + (size_t)(row0 + row) * D_ + (ck) * BKC + gs * 4,  \
                            &Xs[buf][G * 4]);                                     \
            }                                                                     \
        }

    STAGE(0, 0);
    asm volatile("s_waitcnt vmcnt(0)" ::: "memory");
    __syncthreads();

    f32x4 acc0 = {0.f, 0.f, 0.f, 0.f};
    f32x4 acc1 = {0.f, 0.f, 0.f, 0.f};
    const int myrow = w * 16 + lr;
    const int sw    = myrow & 7;
    const ushort* wb0 = &WtS[lr * WT_LD];
    const ushort* wb1 = &WtS[(lr + 16) * WT_LD];

    for (int c = 0; c < D_ / BKC; ++c) {
        if (c < D_ / BKC - 1) STAGE(c + 1, (c + 1) & 1);
        const float* xb = Xs[c & 1];
        #pragma unroll
        for (int kk = 0; kk < 3; ++kk) {
            const int g0 = 8 * kk + 2 * q;
            const f32x4 alo = *(const f32x4*)&xb[(myrow * 24 + (g0 ^ sw)) * 4];
            const f32x4 ahi = *(const f32x4*)&xb[(myrow * 24 + ((g0 + 1) ^ sw)) * 4];
            union { unsigned u[4]; bf16x8 v; } af;
            af.u[0] = cvt_pk_bf16(alo[0], alo[1]);
            af.u[1] = cvt_pk_bf16(alo[2], alo[3]);
            af.u[2] = cvt_pk_bf16(ahi[0], ahi[1]);
            af.u[3] = cvt_pk_bf16(ahi[2], ahi[3]);
            const int kg = c * BKC + kk * 32 + q * 8;
            const bf16x8 b0 = *(const bf16x8*)(wb0 + kg);
            const bf16x8 b1 = *(const bf16x8*)(wb1 + kg);
            acc0 = __builtin_amdgcn_mfma_f32_16x16x32_bf16(af.v, b0, acc0, 0, 0, 0);
            acc1 = __builtin_amdgcn_mfma_f32_16x16x32_bf16(af.v, b1, acc1, 0, 0, 0);
        }
        asm volatile("s_waitcnt vmcnt(0)" ::: "memory");
        __syncthreads();
    }
    #undef STAGE

    const int r0 = row0 + w * 16 + q * 4;   // D: col=lane&15, row=(lane>>4)*4+reg
    #pragma unroll
    for (int reg = 0; reg < 4; ++reg) {
        npots[(size_t)(r0 + reg) * C_ + lr]      = acc0[reg];
        npots[(size_t)(r0 + reg) * C_ + lr + 16] = acc1[reg];
    }
}

// ---------------------------------------------------------------------------
// K2: block (n,k), 128 thr. Wave0: chunk 32x32 product via MFMA.
//     Wave1: score partial for window [32k, 32k+32). No barriers. (unchanged)
// ---------------------------------------------------------------------------
__global__ __launch_bounds__(128) void chunk_score(const float* __restrict__ npots,
                                                   const float* __restrict__ pad,
                                                   const float* __restrict__ T,
                                                   const float* __restrict__ labels,
                                                   float* __restrict__ Bg,
                                                   float* __restrict__ chunk_ls,
                                                   float* __restrict__ scores_p) {
    const int n = blockIdx.x, k = blockIdx.y;
    const int tid = threadIdx.x;
    const int l = tid & 63;
    __shared__ __align__(16) float e_lds[LC * C_];

    if (tid >= 64) {
        const int tb = k * LC;
        int best = 0;
        if (l <= LC) {
            const int t = tb - 1 + l;
            if (t >= 0) {
                const float* lrow = labels + ((size_t)n * S_ + t) * C_;
                float bv = lrow[0];
                #pragma unroll
                for (int c = 1; c < C_; ++c) {
                    const float x = lrow[c];
                    if (x > bv) { bv = x; best = c; }
                }
            }
        }
        const int cur = __shfl(best, l + 1);
        float v = 0.f;
        if (l < LC) {
            const int t = tb + l;
            const float p = pad[(size_t)n * S_ + t];
            v = p * npots[((size_t)n * S_ + t) * C_ + cur];
            if (t >= 1) v = fmaf(p, T[best * C_ + cur], v);
        }
        #pragma unroll
        for (int o = 32; o >= 1; o >>= 1) v += __shfl_xor(v, o);
        if (l == 0) scores_p[n * KCH + k] = v;
        return;
    }

    const int cc = l & 31;
    const int h  = l >> 5;

    const float* pm = pad + (size_t)n * S_;
    float ls = 0.f;
    for (int t = l; t < S_; t += 64) ls += pm[t];
    #pragma unroll
    for (int o = 32; o >= 1; o >>= 1) ls += __shfl_xor(ls, o);
    const int len = (int)(ls + 0.5f);

    float* Bout = Bg + ((size_t)n * KCH + k) * (C_ * C_);
    const int lo = k * LC;
    const int hi = min(lo + LC, len - 1);

    if (lo >= len - 1) {
        #pragma unroll
        for (int qq = 0; qq < 16; ++qq) {
            const int row = (qq & 3) + 8 * (qq >> 2) + 4 * h;
            Bout[row * C_ + cc] = (row == cc) ? 1.f : 0.f;
        }
        if (l == 0) chunk_ls[n * KCH + k] = 0.f;
        return;
    }

    const int cnt = hi - lo;

    const float* npn = npots + ((size_t)n * S_ + lo) * C_;
    for (int qd = l * 4; qd < cnt * C_; qd += 256) {
        const float4 v = *(const float4*)(npn + qd);
        *(float4*)&e_lds[qd] = make_float4(expf(v.x), expf(v.y), expf(v.z), expf(v.w));
    }
    asm volatile("s_waitcnt lgkmcnt(0)" ::: "memory");

    float glo[8], ghi[8];
    {
        const float* el = e_lds + (size_t)(cnt - 1) * C_;
        #pragma unroll
        for (int j = 0; j < 8; ++j) {
            const int kk = 8 * h + j;
            glo[j] = el[kk]      * expf(T[kk * C_ + cc]);
            ghi[j] = el[kk + 16] * expf(T[(kk + 16) * C_ + cc]);
        }
    }

    if (cnt == 1) {
        #pragma unroll
        for (int j = 0; j < 8; ++j) {
            Bout[(8 * h + j) * C_ + cc]      = glo[j];
            Bout[(8 * h + j + 16) * C_ + cc] = ghi[j];
        }
        if (l == 0) chunk_ls[n * KCH + k] = 0.f;
        return;
    }

    union { unsigned u[4]; bf16x8 v; } ETalo, ETahi, blo, bhi;
    #pragma unroll
    for (int t = 0; t < 4; ++t) {
        const int kk = 8 * h + 2 * t;
        ETalo.u[t] = cvt_pk_bf16(expf(T[cc * C_ + kk]),      expf(T[cc * C_ + kk + 1]));
        ETahi.u[t] = cvt_pk_bf16(expf(T[cc * C_ + kk + 16]), expf(T[cc * C_ + kk + 17]));
        blo.u[t]   = cvt_pk_bf16(glo[2 * t], glo[2 * t + 1]);
        bhi.u[t]   = cvt_pk_bf16(ghi[2 * t], ghi[2 * t + 1]);
    }

    float logscale = 0.f;
    int it = 0;
    for (int i = hi - 2; i >= lo; --i) {
        f32x16 d = {};
        d = __builtin_amdgcn_mfma_f32_32x32x16_bf16(ETalo.v, blo.v, d, 0, 0, 0);
        d = __builtin_amdgcn_mfma_f32_32x32x16_bf16(ETahi.v, bhi.v, d, 0, 0, 0);

        const float* ep = e_lds + (i - lo) * C_ + 4 * h;
        const float4 e0 = *(const float4*)(ep);
        const float4 e1 = *(const float4*)(ep + 8);
        const float4 e2 = *(const float4*)(ep + 16);
        const float4 e3 = *(const float4*)(ep + 24);
        float sd[16];
        sd[0]  = d[0]  * e0.x;  sd[1]  = d[1]  * e0.y;  sd[2]  = d[2]  * e0.z;  sd[3]  = d[3]  * e0.w;
        sd[4]  = d[4]  * e1.x;  sd[5]  = d[5]  * e1.y;  sd[6]  = d[6]  * e1.z;  sd[7]  = d[7]  * e1.w;
        sd[8]  = d[8]  * e2.x;  sd[9]  = d[9]  * e2.y;  sd[10] = d[10] * e2.z;  sd[11] = d[11] * e2.w;
        sd[12] = d[12] * e3.x;  sd[13] = d[13] * e3.y;  sd[14] = d[14] * e3.z;  sd[15] = d[15] * e3.w;

        if ((++it & 7) == 0) {
            float m = sd[0];
            #pragma unroll
            for (int qq = 1; qq < 16; ++qq) m = fmaxf(m, sd[qq]);
            #pragma unroll
            for (int o = 32; o >= 1; o >>= 1) m = fmaxf(m, __shfl_xor(m, o));
            logscale += logf(m);
            const float inv = 1.f / m;
            #pragma unroll
            for (int qq = 0; qq < 16; ++qq) sd[qq] *= inv;
        }

        if (i > lo) {
            const unsigned w0 = cvt_pk_bf16(sd[0],  sd[1]);
            const unsigned w1 = cvt_pk_bf16(sd[2],  sd[3]);
            const unsigned w2 = cvt_pk_bf16(sd[4],  sd[5]);
            const unsigned w3 = cvt_pk_bf16(sd[6],  sd[7]);
            const unsigned w4 = cvt_pk_bf16(sd[8],  sd[9]);
            const unsigned w5 = cvt_pk_bf16(sd[10], sd[11]);
            const unsigned w6 = cvt_pk_bf16(sd[12], sd[13]);
            const unsigned w7 = cvt_pk_bf16(sd[14], sd[15]);
            const unsigned x0 = (unsigned)__shfl_xor((int)w0, 32);
            const unsigned x1 = (unsigned)__shfl_xor((int)w1, 32);
            const unsigned x2 = (unsigned)__shfl_xor((int)w2, 32);
            const unsigned x3 = (unsigned)__shfl_xor((int)w3, 32);
            const unsigned x4 = (unsigned)__shfl_xor((int)w4, 32);
            const unsigned x5 = (unsigned)__shfl_xor((int)w5, 32);
            const unsigned x6 = (unsigned)__shfl_xor((int)w6, 32);
            const unsigned x7 = (unsigned)__shfl_xor((int)w7, 32);
            blo.u[0] = h ? x2 : w0;
            blo.u[1] = h ? x3 : w1;
            blo.u[2] = h ? w2 : x0;
            blo.u[3] = h ? w3 : x1;
            bhi.u[0] = h ? x6 : w4;
            bhi.u[1] = h ? x7 : w5;
            bhi.u[2] = h ? w6 : x4;
            bhi.u[3] = h ? w7 : x5;
        } else {
            #pragma unroll
            for (int qq = 0; qq < 16; ++qq)
                Bout[((qq & 3) + 8 * (qq >> 2) + 4 * h) * C_ + cc] = sd[qq];
        }
    }
    if (l == 0) chunk_ls[n * KCH + k] = logscale;
}

// ---------------------------------------------------------------------------
// K3: apply B_{K-1}..B_0 to e_{len-1}; logZ. One wave per n. (unchanged)
// ---------------------------------------------------------------------------
__global__ __launch_bounds__(64) void combine_logZ(const float* __restrict__ npots,
                                                   const float* __restrict__ pad,
                                                   const float* __restrict__ Bg,
                                                   const float* __restrict__ chunk_ls,
                                                   float* __restrict__ logZ) {
    const int n = blockIdx.x;
    const int l = threadIdx.x;
    const int r = l & 31;
    const int h = l >> 5;
    __shared__ __align__(16) float w_lds[32];

    const float* pm = pad + (size_t)n * S_;
    float ls = 0.f;
    for (int t = l; t < S_; t += 64) ls += pm[t];
    #pragma unroll
    for (int o = 32; o >= 1; o >>= 1) ls += __shfl_xor(ls, o);
    const int len = (int)(ls + 0.5f);

    float cls = (l < KCH) ? chunk_ls[n * KCH + l] : 0.f;
    #pragma unroll
    for (int o = 32; o >= 1; o >>= 1) cls += __shfl_xor(cls, o);

    const float np_last = npots[((size_t)n * S_ + (len - 1)) * C_ + r];
    float m0 = np_last;
    #pragma unroll
    for (int o = 32; o >= 1; o >>= 1) m0 = fmaxf(m0, __shfl_xor(m0, o));
    float logscale = m0 + cls;
    if (h == 0) w_lds[r] = expf(np_last - m0);
    __syncthreads();

    float bv[16];
    {
        const float* Brow = Bg + ((size_t)n * KCH + (KCH - 1)) * (C_ * C_) + r * C_ + h * 16;
        #pragma unroll
        for (int t = 0; t < 4; ++t) *(float4*)&bv[t * 4] = *(const float4*)(Brow + t * 4);
    }

    float sn = 0.f;
    for (int k = KCH - 1; k >= 0; --k) {
        float cb[16];
        #pragma unroll
        for (int t = 0; t < 16; ++t) cb[t] = bv[t];
        if (k > 0) {
            const float* Brow = Bg + ((size_t)n * KCH + (k - 1)) * (C_ * C_) + r * C_ + h * 16;
            #pragma unroll
            for (int t = 0; t < 4; ++t) *(float4*)&bv[t * 4] = *(const float4*)(Brow + t * 4);
        }
        float wv[16];
        #pragma unroll
        for (int t = 0; t < 4; ++t) *(float4*)&wv[t * 4] = *(const float4*)&w_lds[h * 16 + t * 4];
        float s = 0.f;
        #pragma unroll
        for (int t = 0; t < 16; ++t) s = fmaf(cb[t], wv[t], s);
        s += __shfl_xor(s, 32);

        float m = s;
        #pragma unroll
        for (int o = 16; o >= 1; o >>= 1) m = fmaxf(m, __shfl_xor(m, o));
        logscale += logf(m);
        sn = s / m;
        __syncthreads();
        if (h == 0) w_lds[r] = sn;
        __syncthreads();
    }

    float v = (h == 0) ? sn : 0.f;
    #pragma unroll
    for (int o = 32; o >= 1; o >>= 1) v += __shfl_xor(v, o);
    if (l == 0) logZ[n] = logf(v) + logscale;
}

// ---------------------------------------------------------------------------
// K4: loss = -mean(score - logZ)
// ---------------------------------------------------------------------------
__global__ __launch_bounds__(64) void finalize(const float* __restrict__ scores_p,
                                               const float* __restrict__ logZ,
                                               float* __restrict__ out) {
    const int l = threadIdx.x;
    float sc = 0.f;
    #pragma unroll
    for (int tb = 0; tb < KCH; ++tb) sc += scores_p[l * KCH + tb];
    float v = sc - logZ[l];
    #pragma unroll
    for (int o = 32; o >= 1; o >>= 1) v += __shfl_xor(v, o);
    if (l == 0) out[0] = -v / (float)N_;
}

// ---------------------------------------------------------------------------
extern "C" void kernel_launch(void* const* d_in, const int* in_sizes, int n_in,
                              void* d_out, int out_size, void* d_ws, size_t ws_size,
                              hipStream_t stream) {
    const float* X      = (const float*)d_in[0];
    const float* W      = (const float*)d_in[1];
    const float* T      = (const float*)d_in[2];
    const float* labels = (const float*)d_in[3];
    const float* pad    = (const float*)d_in[4];
    float* out = (float*)d_out;

    float* npots    = (float*)d_ws;                       // 1,048,576 f
    float* Bg       = npots + (size_t)N_ * S_ * C_;       // 1,048,576 f
    float* chunk_ls = Bg + (size_t)N_ * KCH * C_ * C_;    // 1024 f
    float* logZ     = chunk_ls + N_ * KCH;                // 64 f
    float* scores_p = logZ + N_;                          // 1024 f

    gemm_npots_mfma<<<(N_ * S_) / ROWS_PB, 512, 0, stream>>>(X, W, npots);
    chunk_score<<<dim3(N_, KCH), 128, 0, stream>>>(npots, pad, T, labels, Bg, chunk_ls, scores_p);
    combine_logZ<<<N_, 64, 0, stream>>>(npots, pad, Bg, chunk_ls, logZ);
    finalize<<<1, 64, 0, stream>>>(scores_p, logZ, out);
}